// Round 16
// baseline (112.292 us; speedup 1.0000x reference)
//
#include <hip/hip_runtime.h>
#include <hip/hip_bf16.h>
#include <stdint.h>

#define N_B 4
#define NV 4096
#define NE 2048

typedef float    f32x4  __attribute__((ext_vector_type(4)));
typedef __bf16   bf16x8 __attribute__((ext_vector_type(8)));
typedef unsigned short u16;
typedef u16      u16x8  __attribute__((ext_vector_type(8)));
typedef uint32_t u32x4  __attribute__((ext_vector_type(4)));

__device__ __forceinline__ u16 f2bf_rne(float f) {
    uint32_t u = __builtin_bit_cast(uint32_t, f);
    u += 0x7FFFu + ((u >> 16) & 1u);
    return (u16)(u >> 16);
}
__device__ __forceinline__ float bf2f(u16 h) {
    uint32_t u = ((uint32_t)h) << 16;
    return __builtin_bit_cast(float, u);
}
__device__ __forceinline__ f32x4 mfma_bf16(u16x8 a, u16x8 b, f32x4 c) {
    return __builtin_amdgcn_mfma_f32_16x16x32_bf16(
        __builtin_bit_cast(bf16x8, a), __builtin_bit_cast(bf16x8, b), c, 0, 0, 0);
}
// 8 bits -> 8 bf16 (1.0/0.0). u16 lane j = bit j.
__device__ __forceinline__ u16x8 expand8(uint32_t byte) {
    u32x4 w;
#pragma unroll
    for (int p = 0; p < 4; ++p) {
        const uint32_t lo = (byte >> (2 * p)) & 1u;
        const uint32_t hi = (byte >> (2 * p + 1)) & 1u;
        w[p] = (lo | (hi << 16)) * 0x3F80u;
    }
    return __builtin_bit_cast(u16x8, w);
}

// ---------------------------------------------------------------------------
// Kernel PREP (1 node): uniform 16.64 KB LDS -> 9 blocks/CU.
//  blocks [0,8192): pack one 64x64 H tile -> HB + HT (R13-proven body)
//  blocks [8192,8448): xtheta tile, theta staged in LDS, x streamed float4
//   HB[n][v>>4][e/32][v&15]  (bit = e&31)
//   HT[n][e>>4][v/32][e&15]  (bit = v&31)
// ---------------------------------------------------------------------------
__global__ __launch_bounds__(256) void k_prep(const float* __restrict__ H,
                                              const float* __restrict__ x,
                                              const float* __restrict__ th,
                                              uint32_t* __restrict__ HB,
                                              uint32_t* __restrict__ HT,
                                              u16* __restrict__ Yh,
                                              u16* __restrict__ Yl) {
    __shared__ float smem[64 * 65];   // 16.64 KB, shared by both roles
    const int bid = blockIdx.x;
    const int t = threadIdx.x;

    if (bid < 8192) {
        // ---- pack one 64x64 tile (R13 body, verbatim) ----
        float (*tile)[65] = (float(*)[65])smem;
        const int ex = bid & 31, vy = (bid >> 5) & 63, n = bid >> 11;
        const int e0 = ex * 64, v0 = vy * 64;
        const float* __restrict__ Hn = H + ((size_t)n * NV + v0) * NE + e0;

#pragma unroll
        for (int i = 0; i < 4; ++i) {
            const int idx = i * 256 + t;
            const int row = idx >> 4;
            const int q = (idx & 15) * 4;
            const float4 hv = *(const float4*)(Hn + (size_t)row * NE + q);
            tile[row][q] = hv.x; tile[row][q + 1] = hv.y;
            tile[row][q + 2] = hv.z; tile[row][q + 3] = hv.w;
        }
        __syncthreads();

        if (t < 128) {
            const int v = t >> 1, we = t & 1;
            uint32_t u = 0;
#pragma unroll
            for (int j = 0; j < 32; ++j)
                u |= (tile[v][we * 32 + j] != 0.0f) ? (1u << j) : 0u;
            HB[(((size_t)n * (NV / 16) + ((v0 + v) >> 4)) * (NE / 32) + (e0 >> 5) + we) * 16 +
               ((v0 + v) & 15)] = u;
        } else {
            const int e = (t - 128) >> 1, wv = t & 1;
            uint32_t u = 0;
#pragma unroll
            for (int j = 0; j < 32; ++j)
                u |= (tile[wv * 32 + j][e] != 0.0f) ? (1u << j) : 0u;
            HT[(((size_t)n * (NE / 16) + ((e0 + e) >> 4)) * (NV / 32) + (v0 >> 5) + wv) * 16 +
               ((e0 + e) & 15)] = u;
        }
    } else {
        // ---- xtheta one (n, v0) tile: theta in LDS, x streamed ----
        float (*ts)[65] = (float(*)[65])smem;   // [k][c]
        const int bx = bid - 8192;
        const int n = bx >> 6, v0 = (bx & 63) * 64;

#pragma unroll
        for (int i = 0; i < 4; ++i) {
            const int idx = i * 256 + t;
            const int row = idx >> 4, q = (idx & 15) * 4;
            const float4 tv = *(const float4*)&th[(size_t)row * 64 + q];
            ts[row][q] = tv.x; ts[row][q + 1] = tv.y;
            ts[row][q + 2] = tv.z; ts[row][q + 3] = tv.w;
        }
        __syncthreads();

        const int v4 = (t & 15) * 4;
        const int c4 = (t >> 4) * 4;
        const float* __restrict__ xb = x + ((size_t)(n * NV + v0 + v4)) * 64;

        float acc[4][4] = {};   // [c][v]
#pragma unroll
        for (int kb = 0; kb < 16; ++kb) {
            float4 xr[4];
#pragma unroll
            for (int j = 0; j < 4; ++j)
                xr[j] = *(const float4*)(xb + (size_t)j * 64 + kb * 4);
#pragma unroll
            for (int kk = 0; kk < 4; ++kk) {
                const int k = kb * 4 + kk;
                float tv[4], xv[4];
#pragma unroll
                for (int i = 0; i < 4; ++i) tv[i] = ts[k][c4 + i];
                xv[0] = xr[0][kk]; xv[1] = xr[1][kk];
                xv[2] = xr[2][kk]; xv[3] = xr[3][kk];
#pragma unroll
                for (int i = 0; i < 4; ++i)
#pragma unroll
                    for (int j = 0; j < 4; ++j) acc[i][j] += tv[i] * xv[j];
            }
        }
#pragma unroll
        for (int i = 0; i < 4; ++i) {
            ushort4 hi, lo;
            u16 h;
            h = f2bf_rne(acc[i][0]); hi.x = h; lo.x = f2bf_rne(acc[i][0] - bf2f(h));
            h = f2bf_rne(acc[i][1]); hi.y = h; lo.y = f2bf_rne(acc[i][1] - bf2f(h));
            h = f2bf_rne(acc[i][2]); hi.z = h; lo.z = f2bf_rne(acc[i][2] - bf2f(h));
            h = f2bf_rne(acc[i][3]); hi.w = h; lo.w = f2bf_rne(acc[i][3] - bf2f(h));
            const size_t o = ((size_t)n * 64 + c4 + i) * NV + v0 + v4;
            *(ushort4*)&Yh[o] = hi;
            *(ushort4*)&Yl[o] = lo;
        }
    }
}

// ---------------------------------------------------------------------------
// Kernel 2: vertex->edge MFMA partials + folded degree-from-popcount.
//   P2[sp][n][c][e] = sum_{v in Krange} H[n,v,e]*(Yh+Yl)[n,v,c]
// XCD swizzle; launch_bounds(256,8); A depth-2 + B depth-1.
// ---------------------------------------------------------------------------
__global__ __launch_bounds__(256, 8) void k_v2e(const uint32_t* __restrict__ HT,
                                                const uint32_t* __restrict__ HB,
                                                const u16* __restrict__ Yh,
                                                const u16* __restrict__ Yl,
                                                float* __restrict__ P2,
                                                float* __restrict__ de,
                                                float* __restrict__ dv) {
    const int t = threadIdx.x;
    const int s2 = gridDim.y;
    const int lin = blockIdx.x + 32 * (blockIdx.y + s2 * blockIdx.z);
    const int nb = 32 * s2 * N_B;

    // ---- folded degree collapse via popcount (grid-stride, t<64) ----
    if (t < 64) {
        const int total = N_B * NE + N_B * NV;
        for (int id = lin * 64 + t; id < total; id += nb * 64) {
            if (id < N_B * NE) {
                const int n_ = id >> 11, e = id & (NE - 1);
                const uint32_t* p =
                    HT + ((size_t)n_ * (NE / 16) + (e >> 4)) * ((NV / 32) * 16) + (e & 15);
                uint32_t s = 0;
#pragma unroll 4
                for (int wv = 0; wv < NV / 32; ++wv) s += __popc(p[(size_t)wv * 16]);
                de[id] = (float)s;
            } else {
                const int j = id - N_B * NE;
                const int n_ = j >> 12, v = j & (NV - 1);
                const uint32_t* p =
                    HB + ((size_t)n_ * (NV / 16) + (v >> 4)) * ((NE / 32) * 16) + (v & 15);
                uint32_t s = 0;
#pragma unroll 4
                for (int we = 0; we < NE / 32; ++we) s += __popc(p[(size_t)we * 16]);
                dv[j] = (float)s;
            }
        }
    }

    // ---- XCD-swizzled work decode ----
    const int wid = (lin & 7) * (nb >> 3) + (lin >> 3);
    const int n   = wid / (32 * s2);
    const int rem = wid % (32 * s2);
    const int sp  = rem >> 5;
    const int e0  = (rem & 31) * 64;

    const int krange = NV / s2;
    const int kk0 = sp * krange;
    const int S   = krange / 32;   // 8 at s2=16

    const int w = t >> 6, l = t & 63;
    const int lq = l >> 4, lr = l & 15;
    const int sh = lq * 8;
    const int hstride = (NV / 32) * 16;

    const uint32_t* __restrict__ ht =
        HT + ((size_t)n * (NE / 16) + (e0 >> 4)) * hstride + (kk0 >> 5) * 16 + lr;
    const u16* __restrict__ ybh = Yh + ((size_t)n * 64 + w * 16 + lr) * NV + kk0 + lq * 8;
    const u16* __restrict__ ybl = Yl + ((size_t)n * 64 + w * 16 + lr) * NV + kk0 + lq * 8;

    f32x4 acc0 = {0.f,0.f,0.f,0.f}, acc1 = acc0, acc2 = acc0, acc3 = acc0;

    uint32_t A[2][4];
#pragma unroll
    for (int d = 0; d < 2; ++d) {
        A[d][0] = ht[0 * hstride + d * 16];
        A[d][1] = ht[1 * hstride + d * 16];
        A[d][2] = ht[2 * hstride + d * 16];
        A[d][3] = ht[3 * hstride + d * 16];
    }
    u16x8 BH[2], BL[2];
    BH[0] = *(const u16x8*)ybh;
    BL[0] = *(const u16x8*)ybl;

#define V2E_STEP(s, u, GA, GB)                                                \
    {                                                                         \
        const uint32_t a0 = A[u][0], a1 = A[u][1], a2 = A[u][2], a3 = A[u][3];\
        if (GA) {                                                             \
            A[u][0] = ht[0 * hstride + ((s) + 2) * 16];                       \
            A[u][1] = ht[1 * hstride + ((s) + 2) * 16];                       \
            A[u][2] = ht[2 * hstride + ((s) + 2) * 16];                       \
            A[u][3] = ht[3 * hstride + ((s) + 2) * 16];                       \
        }                                                                     \
        if (GB) {                                                             \
            BH[((u) + 1) & 1] = *(const u16x8*)(ybh + ((s) + 1) * 32);        \
            BL[((u) + 1) & 1] = *(const u16x8*)(ybl + ((s) + 1) * 32);        \
        }                                                                     \
        const u16x8 bh = BH[u], bl = BL[u];                                   \
        u16x8 a;                                                              \
        a = expand8((a0 >> sh) & 0xFF);                                       \
        acc0 = mfma_bf16(a, bh, acc0); acc0 = mfma_bf16(a, bl, acc0);         \
        a = expand8((a1 >> sh) & 0xFF);                                       \
        acc1 = mfma_bf16(a, bh, acc1); acc1 = mfma_bf16(a, bl, acc1);         \
        a = expand8((a2 >> sh) & 0xFF);                                       \
        acc2 = mfma_bf16(a, bh, acc2); acc2 = mfma_bf16(a, bl, acc2);         \
        a = expand8((a3 >> sh) & 0xFF);                                       \
        acc3 = mfma_bf16(a, bh, acc3); acc3 = mfma_bf16(a, bl, acc3);         \
    }

    int sb = 0;
    for (; sb < S - 2; sb += 2) {
        V2E_STEP(sb + 0, 0, true, true)
        V2E_STEP(sb + 1, 1, true, true)
    }
    V2E_STEP(sb + 0, 0, false, true)
    V2E_STEP(sb + 1, 1, false, false)
#undef V2E_STEP

    // D: row e = e0 + eb*16 + lq*4 + reg, col c = w*16 + lr
    float* pb = P2 + (((size_t)sp * N_B + n) * 64 + w * 16 + lr) * NE + e0 + lq * 4;
    *(f32x4*)(pb + 0)  = acc0;
    *(f32x4*)(pb + 16) = acc1;
    *(f32x4*)(pb + 32) = acc2;
    *(f32x4*)(pb + 48) = acc3;
}

// ---------------------------------------------------------------------------
// Kernel 3: Z_{h,l}[n][c][e] = bf16 hi/lo of (sum_sp P2)/de
// ---------------------------------------------------------------------------
__global__ __launch_bounds__(256) void k_red2(const float* __restrict__ P2,
                                              const float* __restrict__ de,
                                              u16* __restrict__ Zh,
                                              u16* __restrict__ Zl, int nsp) {
    const int i = blockIdx.x * 256 + threadIdx.x;   // 0..131071
    const int row = i >> 9;                          // n*64 + c
    const int e4  = (i & 511) * 4;
    const int n   = row >> 6;

    float4 a = make_float4(0.f, 0.f, 0.f, 0.f);
    for (int sp = 0; sp < nsp; ++sp) {
        const float4 p = *(const float4*)&P2[((size_t)sp * 256 + row) * NE + e4];
        a.x += p.x; a.y += p.y; a.z += p.z; a.w += p.w;
    }
    const float4 d = *(const float4*)&de[(size_t)n * NE + e4];
    float z[4] = {a.x / d.x, a.y / d.y, a.z / d.z, a.w / d.w};
    ushort4 hi, lo;
    u16 h;
    h = f2bf_rne(z[0]); hi.x = h; lo.x = f2bf_rne(z[0] - bf2f(h));
    h = f2bf_rne(z[1]); hi.y = h; lo.y = f2bf_rne(z[1] - bf2f(h));
    h = f2bf_rne(z[2]); hi.z = h; lo.z = f2bf_rne(z[2] - bf2f(h));
    h = f2bf_rne(z[3]); hi.w = h; lo.w = f2bf_rne(z[3] - bf2f(h));
    *(ushort4*)&Zh[(size_t)row * NE + e4] = hi;
    *(ushort4*)&Zl[(size_t)row * NE + e4] = lo;
}

// ---------------------------------------------------------------------------
// Kernel 4: edge->vertex MFMA partials. Same structure as k_v2e.
// ---------------------------------------------------------------------------
__global__ __launch_bounds__(256, 8) void k_e2v(const uint32_t* __restrict__ HB,
                                                const u16* __restrict__ Zh,
                                                const u16* __restrict__ Zl,
                                                float* __restrict__ P3) {
    const int t = threadIdx.x;
    const int s3 = gridDim.y;
    const int lin = blockIdx.x + 64 * (blockIdx.y + s3 * blockIdx.z);
    const int nb = 64 * s3 * N_B;

    const int wid = (lin & 7) * (nb >> 3) + (lin >> 3);
    const int n   = wid / (64 * s3);
    const int rem = wid % (64 * s3);
    const int sp  = rem >> 6;
    const int v0  = (rem & 63) * 64;

    const int krange = NE / s3;
    const int kk0 = sp * krange;
    const int S   = krange / 32;   // 8 at s3=8

    const int w = t >> 6, l = t & 63;
    const int lq = l >> 4, lr = l & 15;
    const int sh = lq * 8;
    const int estride = (NE / 32) * 16;

    const uint32_t* __restrict__ hb =
        HB + ((size_t)n * (NV / 16) + (v0 >> 4)) * estride + (kk0 >> 5) * 16 + lr;
    const u16* __restrict__ zbh = Zh + ((size_t)n * 64 + w * 16 + lr) * NE + kk0 + lq * 8;
    const u16* __restrict__ zbl = Zl + ((size_t)n * 64 + w * 16 + lr) * NE + kk0 + lq * 8;

    f32x4 acc0 = {0.f,0.f,0.f,0.f}, acc1 = acc0, acc2 = acc0, acc3 = acc0;

    uint32_t A[2][4];
#pragma unroll
    for (int d = 0; d < 2; ++d) {
        A[d][0] = hb[0 * estride + d * 16];
        A[d][1] = hb[1 * estride + d * 16];
        A[d][2] = hb[2 * estride + d * 16];
        A[d][3] = hb[3 * estride + d * 16];
    }
    u16x8 BH[2], BL[2];
    BH[0] = *(const u16x8*)zbh;
    BL[0] = *(const u16x8*)zbl;

#define E2V_STEP(s, u, GA, GB)                                                \
    {                                                                         \
        const uint32_t a0 = A[u][0], a1 = A[u][1], a2 = A[u][2], a3 = A[u][3];\
        if (GA) {                                                             \
            A[u][0] = hb[0 * estride + ((s) + 2) * 16];                       \
            A[u][1] = hb[1 * estride + ((s) + 2) * 16];                       \
            A[u][2] = hb[2 * estride + ((s) + 2) * 16];                       \
            A[u][3] = hb[3 * estride + ((s) + 2) * 16];                       \
        }                                                                     \
        if (GB) {                                                             \
            BH[((u) + 1) & 1] = *(const u16x8*)(zbh + ((s) + 1) * 32);        \
            BL[((u) + 1) & 1] = *(const u16x8*)(zbl + ((s) + 1) * 32);        \
        }                                                                     \
        const u16x8 bh = BH[u], bl = BL[u];                                   \
        u16x8 a;                                                              \
        a = expand8((a0 >> sh) & 0xFF);                                       \
        acc0 = mfma_bf16(a, bh, acc0); acc0 = mfma_bf16(a, bl, acc0);         \
        a = expand8((a1 >> sh) & 0xFF);                                       \
        acc1 = mfma_bf16(a, bh, acc1); acc1 = mfma_bf16(a, bl, acc1);         \
        a = expand8((a2 >> sh) & 0xFF);                                       \
        acc2 = mfma_bf16(a, bh, acc2); acc2 = mfma_bf16(a, bl, acc2);         \
        a = expand8((a3 >> sh) & 0xFF);                                       \
        acc3 = mfma_bf16(a, bh, acc3); acc3 = mfma_bf16(a, bl, acc3);         \
    }

    int sb = 0;
    for (; sb < S - 2; sb += 2) {
        E2V_STEP(sb + 0, 0, true, true)
        E2V_STEP(sb + 1, 1, true, true)
    }
    E2V_STEP(sb + 0, 0, false, true)
    E2V_STEP(sb + 1, 1, false, false)
#undef E2V_STEP

    float* pb = P3 + (((size_t)sp * N_B + n) * 64 + w * 16 + lr) * NV + v0 + lq * 4;
    *(f32x4*)(pb + 0)  = acc0;
    *(f32x4*)(pb + 16) = acc1;
    *(f32x4*)(pb + 32) = acc2;
    *(f32x4*)(pb + 48) = acc3;
}

// ---------------------------------------------------------------------------
// Kernel 5: out[n][v][c] = (sum_sp P3[sp][n][c][v]) / dv + bias  (transpose)
// ---------------------------------------------------------------------------
__global__ __launch_bounds__(512) void k_red3(const float* __restrict__ P3,
                                              const float* __restrict__ dv,
                                              const float* __restrict__ bias,
                                              float* __restrict__ out, int nsp) {
    __shared__ float lt[64][68];
    const int n  = blockIdx.y;
    const int v0 = blockIdx.x * 64;
    const int t  = threadIdx.x;

    {
        const int c   = t >> 3;
        const int vch = (t & 7) * 8;
        float4 s0 = make_float4(0.f, 0.f, 0.f, 0.f), s1 = s0;
        for (int sp = 0; sp < nsp; ++sp) {
            const size_t base = (((size_t)sp * N_B + n) * 64 + c) * NV + v0 + vch;
            const float4 p0 = *(const float4*)&P3[base];
            const float4 p1 = *(const float4*)&P3[base + 4];
            s0.x += p0.x; s0.y += p0.y; s0.z += p0.z; s0.w += p0.w;
            s1.x += p1.x; s1.y += p1.y; s1.z += p1.z; s1.w += p1.w;
        }
        *(float4*)&lt[c][vch]     = s0;
        *(float4*)&lt[c][vch + 4] = s1;
    }
    const int vw  = t >> 3;
    const int cch = (t & 7) * 8;
    const float dsum = dv[(size_t)n * NV + v0 + vw];
    __syncthreads();

    const float rdv = 1.0f / dsum;
    const float4 b0 = *(const float4*)&bias[cch];
    const float4 b1 = *(const float4*)&bias[cch + 4];
    float4 o0, o1;
    o0.x = lt[cch + 0][vw] * rdv + b0.x;
    o0.y = lt[cch + 1][vw] * rdv + b0.y;
    o0.z = lt[cch + 2][vw] * rdv + b0.z;
    o0.w = lt[cch + 3][vw] * rdv + b0.w;
    o1.x = lt[cch + 4][vw] * rdv + b1.x;
    o1.y = lt[cch + 5][vw] * rdv + b1.y;
    o1.z = lt[cch + 6][vw] * rdv + b1.z;
    o1.w = lt[cch + 7][vw] * rdv + b1.w;
    float* dst = out + ((size_t)n * NV + v0 + vw) * 64 + cch;
    *(float4*)dst       = o0;
    *(float4*)(dst + 4) = o1;
}

// ---------------------------------------------------------------------------
extern "C" void kernel_launch(void* const* d_in, const int* in_sizes, int n_in,
                              void* d_out, int out_size, void* d_ws, size_t ws_size,
                              hipStream_t stream) {
    const float* x     = (const float*)d_in[0];
    const float* H     = (const float*)d_in[1];
    const float* theta = (const float*)d_in[2];
    const float* bias  = (const float*)d_in[3];
    float* out = (float*)d_out;

    const size_t yE  = (size_t)N_B * 64 * NV;        // 1,048,576
    const size_t zE  = (size_t)N_B * 64 * NE;        //   524,288
    const size_t HBW = (size_t)N_B * (NV / 16) * (NE / 32) * 16;
    const size_t HTW = (size_t)N_B * (NE / 16) * (NV / 32) * 16;
    const size_t deE = (size_t)N_B * NE;
    const size_t dvE = (size_t)N_B * NV;

    u16* Yh = (u16*)d_ws;
    u16* Yl = Yh + yE;
    u16* Zh = Yl + yE;
    u16* Zl = Zh + zE;
    uint32_t* HB = (uint32_t*)(Zl + zE);
    uint32_t* HT = HB + HBW;
    float* de = (float*)(HT + HTW);
    float* dv = de + deE;
    float* fbase = dv + dvE;

    const size_t fixed_bytes = (size_t)((char*)fbase - (char*)d_ws);
    const size_t avail_f = (ws_size > fixed_bytes) ? (ws_size - fixed_bytes) / 4 : 0;

    // s2/s3 tiers: S must stay even and >= 4
    int s2 = 2, s3 = 1;
    if      (avail_f >= 16 * zE + 8 * yE) { s2 = 16; s3 = 8; }
    else if (avail_f >=  8 * zE + 4 * yE) { s2 = 8;  s3 = 4; }
    else if (avail_f >=  4 * zE + 2 * yE) { s2 = 4;  s3 = 2; }

    float* P2 = fbase;
    float* P3 = P2 + (size_t)s2 * zE;

    k_prep<<<dim3(8192 + 256), 256, 0, stream>>>(H, x, theta, HB, HT, Yh, Yl);
    k_v2e<<<dim3(NE / 64, s2, N_B), 256, 0, stream>>>(HT, HB, Yh, Yl, P2, de, dv);
    k_red2<<<dim3((int)(zE / 4 / 256)), 256, 0, stream>>>(P2, de, Zh, Zl, s2);
    k_e2v<<<dim3(NV / 64, s3, N_B), 256, 0, stream>>>(HB, Zh, Zl, P3);
    k_red3<<<dim3(NV / 64, N_B), 512, 0, stream>>>(P3, dv, bias, out, s3);
}

// Round 17
// 107.322 us; speedup vs baseline: 1.0463x; 1.0463x over previous
//
#include <hip/hip_runtime.h>
#include <hip/hip_bf16.h>
#include <stdint.h>

#define N_B 4
#define NV 4096
#define NE 2048

typedef float    f32x4  __attribute__((ext_vector_type(4)));
typedef __bf16   bf16x8 __attribute__((ext_vector_type(8)));
typedef unsigned short u16;
typedef u16      u16x8  __attribute__((ext_vector_type(8)));
typedef uint32_t u32x4  __attribute__((ext_vector_type(4)));

__device__ __forceinline__ u16 f2bf_rne(float f) {
    uint32_t u = __builtin_bit_cast(uint32_t, f);
    u += 0x7FFFu + ((u >> 16) & 1u);
    return (u16)(u >> 16);
}
__device__ __forceinline__ float bf2f(u16 h) {
    uint32_t u = ((uint32_t)h) << 16;
    return __builtin_bit_cast(float, u);
}
__device__ __forceinline__ f32x4 mfma_bf16(u16x8 a, u16x8 b, f32x4 c) {
    return __builtin_amdgcn_mfma_f32_16x16x32_bf16(
        __builtin_bit_cast(bf16x8, a), __builtin_bit_cast(bf16x8, b), c, 0, 0, 0);
}
// 8 bits -> 8 bf16 (1.0/0.0). u16 lane j = bit j.
__device__ __forceinline__ u16x8 expand8(uint32_t byte) {
    u32x4 w;
#pragma unroll
    for (int p = 0; p < 4; ++p) {
        const uint32_t lo = (byte >> (2 * p)) & 1u;
        const uint32_t hi = (byte >> (2 * p + 1)) & 1u;
        w[p] = (lo | (hi << 16)) * 0x3F80u;
    }
    return __builtin_bit_cast(u16x8, w);
}

// ---------------------------------------------------------------------------
// Kernel PREP: persistent pipelined pack + xtheta. 16.64 KB LDS.
//  blocks [0,2048): pack FOUR consecutive-ex 64x64 H tiles with a register
//    pipeline: load(tile k+1)->regs issued BEFORE build(tile k), so the
//    bit-build covers the next tile's HBM latency (continuous load issue).
//  blocks [2048,2304): xtheta tile (theta in LDS, x streamed).
//   HB[n][v>>4][e/32][v&15]  (bit = e&31)
//   HT[n][e>>4][v/32][e&15]  (bit = v&31)
// ---------------------------------------------------------------------------
__global__ __launch_bounds__(256) void k_prep(const float* __restrict__ H,
                                              const float* __restrict__ x,
                                              const float* __restrict__ th,
                                              uint32_t* __restrict__ HB,
                                              uint32_t* __restrict__ HT,
                                              u16* __restrict__ Yh,
                                              u16* __restrict__ Yl) {
    __shared__ float smem[64 * 65];   // 16.64 KB
    const int bid = blockIdx.x;
    const int t = threadIdx.x;

    if (bid < 2048) {
        float (*tile)[65] = (float(*)[65])smem;
        const int srow = t >> 4;           // staging row 0..15 (x4 groups)
        const int sq   = (t & 15) * 4;     // staging col
        // 4 tiles: tid = bid*4 + k  -> ex = tid&31, vy = (tid>>5)&63, n = tid>>11
        float4 R0, R1, R2, R3;

#define LOADT(tid)                                                            \
        {                                                                     \
            const int ex_ = (tid) & 31, vy_ = ((tid) >> 5) & 63, n_ = (tid) >> 11; \
            const float* __restrict__ Hn_ =                                   \
                H + ((size_t)n_ * NV + vy_ * 64) * NE + ex_ * 64;             \
            R0 = *(const float4*)(Hn_ + (size_t)(srow +  0) * NE + sq);       \
            R1 = *(const float4*)(Hn_ + (size_t)(srow + 16) * NE + sq);       \
            R2 = *(const float4*)(Hn_ + (size_t)(srow + 32) * NE + sq);       \
            R3 = *(const float4*)(Hn_ + (size_t)(srow + 48) * NE + sq);       \
        }
#define STORET()                                                              \
        {                                                                     \
            *(float4*)&tile[srow +  0][sq] = R0;                              \
            *(float4*)&tile[srow + 16][sq] = R1;                              \
            *(float4*)&tile[srow + 32][sq] = R2;                              \
            *(float4*)&tile[srow + 48][sq] = R3;                              \
        }
#define BUILDT(tid)                                                           \
        {                                                                     \
            const int ex_ = (tid) & 31, vy_ = ((tid) >> 5) & 63, n_ = (tid) >> 11; \
            const int e0_ = ex_ * 64, v0_ = vy_ * 64;                         \
            if (t < 128) {                                                    \
                const int v = t >> 1, we = t & 1;                             \
                uint32_t u = 0;                                               \
                _Pragma("unroll")                                             \
                for (int q = 0; q < 8; ++q) {                                 \
                    const f32x4 f = *(const f32x4*)&tile[v][we * 32 + q * 4]; \
                    u |= (f[0] != 0.0f ? 1u : 0u) << (4 * q + 0);             \
                    u |= (f[1] != 0.0f ? 1u : 0u) << (4 * q + 1);             \
                    u |= (f[2] != 0.0f ? 1u : 0u) << (4 * q + 2);             \
                    u |= (f[3] != 0.0f ? 1u : 0u) << (4 * q + 3);             \
                }                                                             \
                HB[(((size_t)n_ * (NV / 16) + ((v0_ + v) >> 4)) * (NE / 32) + \
                    (e0_ >> 5) + we) * 16 + ((v0_ + v) & 15)] = u;            \
            } else {                                                          \
                const int e = (t - 128) >> 1, wv = t & 1;                     \
                uint32_t u = 0;                                               \
                _Pragma("unroll")                                             \
                for (int j = 0; j < 32; ++j)                                  \
                    u |= (tile[wv * 32 + j][e] != 0.0f) ? (1u << j) : 0u;     \
                HT[(((size_t)n_ * (NE / 16) + ((e0_ + e) >> 4)) * (NV / 32) + \
                    (v0_ >> 5) + wv) * 16 + ((e0_ + e) & 15)] = u;            \
            }                                                                 \
        }

        LOADT(bid * 4 + 0)
        __syncthreads();           // (no-op first time; uniform structure)
        STORET()
        __syncthreads();
        LOADT(bid * 4 + 1)
        BUILDT(bid * 4 + 0)

        __syncthreads();           // build 0 done reading LDS
        STORET()
        __syncthreads();
        LOADT(bid * 4 + 2)
        BUILDT(bid * 4 + 1)

        __syncthreads();
        STORET()
        __syncthreads();
        LOADT(bid * 4 + 3)
        BUILDT(bid * 4 + 2)

        __syncthreads();
        STORET()
        __syncthreads();
        BUILDT(bid * 4 + 3)
#undef LOADT
#undef STORET
#undef BUILDT
    } else {
        // ---- xtheta one (n, v0) tile: theta in LDS, x streamed ----
        float (*ts)[65] = (float(*)[65])smem;   // [k][c]
        const int bx = bid - 2048;
        const int n = bx >> 6, v0 = (bx & 63) * 64;

#pragma unroll
        for (int i = 0; i < 4; ++i) {
            const int idx = i * 256 + t;
            const int row = idx >> 4, q = (idx & 15) * 4;
            const float4 tv = *(const float4*)&th[(size_t)row * 64 + q];
            ts[row][q] = tv.x; ts[row][q + 1] = tv.y;
            ts[row][q + 2] = tv.z; ts[row][q + 3] = tv.w;
        }
        __syncthreads();

        const int v4 = (t & 15) * 4;
        const int c4 = (t >> 4) * 4;
        const float* __restrict__ xb = x + ((size_t)(n * NV + v0 + v4)) * 64;

        float acc[4][4] = {};   // [c][v]
#pragma unroll
        for (int kb = 0; kb < 16; ++kb) {
            float4 xr[4];
#pragma unroll
            for (int j = 0; j < 4; ++j)
                xr[j] = *(const float4*)(xb + (size_t)j * 64 + kb * 4);
#pragma unroll
            for (int kk = 0; kk < 4; ++kk) {
                const int k = kb * 4 + kk;
                float tv[4], xv[4];
#pragma unroll
                for (int i = 0; i < 4; ++i) tv[i] = ts[k][c4 + i];
                xv[0] = xr[0][kk]; xv[1] = xr[1][kk];
                xv[2] = xr[2][kk]; xv[3] = xr[3][kk];
#pragma unroll
                for (int i = 0; i < 4; ++i)
#pragma unroll
                    for (int j = 0; j < 4; ++j) acc[i][j] += tv[i] * xv[j];
            }
        }
#pragma unroll
        for (int i = 0; i < 4; ++i) {
            ushort4 hi, lo;
            u16 h;
            h = f2bf_rne(acc[i][0]); hi.x = h; lo.x = f2bf_rne(acc[i][0] - bf2f(h));
            h = f2bf_rne(acc[i][1]); hi.y = h; lo.y = f2bf_rne(acc[i][1] - bf2f(h));
            h = f2bf_rne(acc[i][2]); hi.z = h; lo.z = f2bf_rne(acc[i][2] - bf2f(h));
            h = f2bf_rne(acc[i][3]); hi.w = h; lo.w = f2bf_rne(acc[i][3] - bf2f(h));
            const size_t o = ((size_t)n * 64 + c4 + i) * NV + v0 + v4;
            *(ushort4*)&Yh[o] = hi;
            *(ushort4*)&Yl[o] = lo;
        }
    }
}

// ---------------------------------------------------------------------------
// Kernel 2: vertex->edge MFMA partials + folded degree-from-popcount.
//   P2[sp][n][c][e] = sum_{v in Krange} H[n,v,e]*(Yh+Yl)[n,v,c]
// XCD swizzle; launch_bounds(256,8); A depth-2 + B depth-1.
// ---------------------------------------------------------------------------
__global__ __launch_bounds__(256, 8) void k_v2e(const uint32_t* __restrict__ HT,
                                                const uint32_t* __restrict__ HB,
                                                const u16* __restrict__ Yh,
                                                const u16* __restrict__ Yl,
                                                float* __restrict__ P2,
                                                float* __restrict__ de,
                                                float* __restrict__ dv) {
    const int t = threadIdx.x;
    const int s2 = gridDim.y;
    const int lin = blockIdx.x + 32 * (blockIdx.y + s2 * blockIdx.z);
    const int nb = 32 * s2 * N_B;

    // ---- folded degree collapse via popcount (grid-stride, t<64) ----
    if (t < 64) {
        const int total = N_B * NE + N_B * NV;
        for (int id = lin * 64 + t; id < total; id += nb * 64) {
            if (id < N_B * NE) {
                const int n_ = id >> 11, e = id & (NE - 1);
                const uint32_t* p =
                    HT + ((size_t)n_ * (NE / 16) + (e >> 4)) * ((NV / 32) * 16) + (e & 15);
                uint32_t s = 0;
#pragma unroll 4
                for (int wv = 0; wv < NV / 32; ++wv) s += __popc(p[(size_t)wv * 16]);
                de[id] = (float)s;
            } else {
                const int j = id - N_B * NE;
                const int n_ = j >> 12, v = j & (NV - 1);
                const uint32_t* p =
                    HB + ((size_t)n_ * (NV / 16) + (v >> 4)) * ((NE / 32) * 16) + (v & 15);
                uint32_t s = 0;
#pragma unroll 4
                for (int we = 0; we < NE / 32; ++we) s += __popc(p[(size_t)we * 16]);
                dv[j] = (float)s;
            }
        }
    }

    // ---- XCD-swizzled work decode ----
    const int wid = (lin & 7) * (nb >> 3) + (lin >> 3);
    const int n   = wid / (32 * s2);
    const int rem = wid % (32 * s2);
    const int sp  = rem >> 5;
    const int e0  = (rem & 31) * 64;

    const int krange = NV / s2;
    const int kk0 = sp * krange;
    const int S   = krange / 32;   // 8 at s2=16

    const int w = t >> 6, l = t & 63;
    const int lq = l >> 4, lr = l & 15;
    const int sh = lq * 8;
    const int hstride = (NV / 32) * 16;

    const uint32_t* __restrict__ ht =
        HT + ((size_t)n * (NE / 16) + (e0 >> 4)) * hstride + (kk0 >> 5) * 16 + lr;
    const u16* __restrict__ ybh = Yh + ((size_t)n * 64 + w * 16 + lr) * NV + kk0 + lq * 8;
    const u16* __restrict__ ybl = Yl + ((size_t)n * 64 + w * 16 + lr) * NV + kk0 + lq * 8;

    f32x4 acc0 = {0.f,0.f,0.f,0.f}, acc1 = acc0, acc2 = acc0, acc3 = acc0;

    uint32_t A[2][4];
#pragma unroll
    for (int d = 0; d < 2; ++d) {
        A[d][0] = ht[0 * hstride + d * 16];
        A[d][1] = ht[1 * hstride + d * 16];
        A[d][2] = ht[2 * hstride + d * 16];
        A[d][3] = ht[3 * hstride + d * 16];
    }
    u16x8 BH[2], BL[2];
    BH[0] = *(const u16x8*)ybh;
    BL[0] = *(const u16x8*)ybl;

#define V2E_STEP(s, u, GA, GB)                                                \
    {                                                                         \
        const uint32_t a0 = A[u][0], a1 = A[u][1], a2 = A[u][2], a3 = A[u][3];\
        if (GA) {                                                             \
            A[u][0] = ht[0 * hstride + ((s) + 2) * 16];                       \
            A[u][1] = ht[1 * hstride + ((s) + 2) * 16];                       \
            A[u][2] = ht[2 * hstride + ((s) + 2) * 16];                       \
            A[u][3] = ht[3 * hstride + ((s) + 2) * 16];                       \
        }                                                                     \
        if (GB) {                                                             \
            BH[((u) + 1) & 1] = *(const u16x8*)(ybh + ((s) + 1) * 32);        \
            BL[((u) + 1) & 1] = *(const u16x8*)(ybl + ((s) + 1) * 32);        \
        }                                                                     \
        const u16x8 bh = BH[u], bl = BL[u];                                   \
        u16x8 a;                                                              \
        a = expand8((a0 >> sh) & 0xFF);                                       \
        acc0 = mfma_bf16(a, bh, acc0); acc0 = mfma_bf16(a, bl, acc0);         \
        a = expand8((a1 >> sh) & 0xFF);                                       \
        acc1 = mfma_bf16(a, bh, acc1); acc1 = mfma_bf16(a, bl, acc1);         \
        a = expand8((a2 >> sh) & 0xFF);                                       \
        acc2 = mfma_bf16(a, bh, acc2); acc2 = mfma_bf16(a, bl, acc2);         \
        a = expand8((a3 >> sh) & 0xFF);                                       \
        acc3 = mfma_bf16(a, bh, acc3); acc3 = mfma_bf16(a, bl, acc3);         \
    }

    int sb = 0;
    for (; sb < S - 2; sb += 2) {
        V2E_STEP(sb + 0, 0, true, true)
        V2E_STEP(sb + 1, 1, true, true)
    }
    V2E_STEP(sb + 0, 0, false, true)
    V2E_STEP(sb + 1, 1, false, false)
#undef V2E_STEP

    // D: row e = e0 + eb*16 + lq*4 + reg, col c = w*16 + lr
    float* pb = P2 + (((size_t)sp * N_B + n) * 64 + w * 16 + lr) * NE + e0 + lq * 4;
    *(f32x4*)(pb + 0)  = acc0;
    *(f32x4*)(pb + 16) = acc1;
    *(f32x4*)(pb + 32) = acc2;
    *(f32x4*)(pb + 48) = acc3;
}

// ---------------------------------------------------------------------------
// Kernel 3: Z_{h,l}[n][c][e] = bf16 hi/lo of (sum_sp P2)/de
// ---------------------------------------------------------------------------
__global__ __launch_bounds__(256) void k_red2(const float* __restrict__ P2,
                                              const float* __restrict__ de,
                                              u16* __restrict__ Zh,
                                              u16* __restrict__ Zl, int nsp) {
    const int i = blockIdx.x * 256 + threadIdx.x;   // 0..131071
    const int row = i >> 9;                          // n*64 + c
    const int e4  = (i & 511) * 4;
    const int n   = row >> 6;

    float4 a = make_float4(0.f, 0.f, 0.f, 0.f);
    for (int sp = 0; sp < nsp; ++sp) {
        const float4 p = *(const float4*)&P2[((size_t)sp * 256 + row) * NE + e4];
        a.x += p.x; a.y += p.y; a.z += p.z; a.w += p.w;
    }
    const float4 d = *(const float4*)&de[(size_t)n * NE + e4];
    float z[4] = {a.x / d.x, a.y / d.y, a.z / d.z, a.w / d.w};
    ushort4 hi, lo;
    u16 h;
    h = f2bf_rne(z[0]); hi.x = h; lo.x = f2bf_rne(z[0] - bf2f(h));
    h = f2bf_rne(z[1]); hi.y = h; lo.y = f2bf_rne(z[1] - bf2f(h));
    h = f2bf_rne(z[2]); hi.z = h; lo.z = f2bf_rne(z[2] - bf2f(h));
    h = f2bf_rne(z[3]); hi.w = h; lo.w = f2bf_rne(z[3] - bf2f(h));
    *(ushort4*)&Zh[(size_t)row * NE + e4] = hi;
    *(ushort4*)&Zl[(size_t)row * NE + e4] = lo;
}

// ---------------------------------------------------------------------------
// Kernel 4: edge->vertex MFMA partials. Same structure as k_v2e.
// ---------------------------------------------------------------------------
__global__ __launch_bounds__(256, 8) void k_e2v(const uint32_t* __restrict__ HB,
                                                const u16* __restrict__ Zh,
                                                const u16* __restrict__ Zl,
                                                float* __restrict__ P3) {
    const int t = threadIdx.x;
    const int s3 = gridDim.y;
    const int lin = blockIdx.x + 64 * (blockIdx.y + s3 * blockIdx.z);
    const int nb = 64 * s3 * N_B;

    const int wid = (lin & 7) * (nb >> 3) + (lin >> 3);
    const int n   = wid / (64 * s3);
    const int rem = wid % (64 * s3);
    const int sp  = rem >> 6;
    const int v0  = (rem & 63) * 64;

    const int krange = NE / s3;
    const int kk0 = sp * krange;
    const int S   = krange / 32;   // 8 at s3=8

    const int w = t >> 6, l = t & 63;
    const int lq = l >> 4, lr = l & 15;
    const int sh = lq * 8;
    const int estride = (NE / 32) * 16;

    const uint32_t* __restrict__ hb =
        HB + ((size_t)n * (NV / 16) + (v0 >> 4)) * estride + (kk0 >> 5) * 16 + lr;
    const u16* __restrict__ zbh = Zh + ((size_t)n * 64 + w * 16 + lr) * NE + kk0 + lq * 8;
    const u16* __restrict__ zbl = Zl + ((size_t)n * 64 + w * 16 + lr) * NE + kk0 + lq * 8;

    f32x4 acc0 = {0.f,0.f,0.f,0.f}, acc1 = acc0, acc2 = acc0, acc3 = acc0;

    uint32_t A[2][4];
#pragma unroll
    for (int d = 0; d < 2; ++d) {
        A[d][0] = hb[0 * estride + d * 16];
        A[d][1] = hb[1 * estride + d * 16];
        A[d][2] = hb[2 * estride + d * 16];
        A[d][3] = hb[3 * estride + d * 16];
    }
    u16x8 BH[2], BL[2];
    BH[0] = *(const u16x8*)zbh;
    BL[0] = *(const u16x8*)zbl;

#define E2V_STEP(s, u, GA, GB)                                                \
    {                                                                         \
        const uint32_t a0 = A[u][0], a1 = A[u][1], a2 = A[u][2], a3 = A[u][3];\
        if (GA) {                                                             \
            A[u][0] = hb[0 * estride + ((s) + 2) * 16];                       \
            A[u][1] = hb[1 * estride + ((s) + 2) * 16];                       \
            A[u][2] = hb[2 * estride + ((s) + 2) * 16];                       \
            A[u][3] = hb[3 * estride + ((s) + 2) * 16];                       \
        }                                                                     \
        if (GB) {                                                             \
            BH[((u) + 1) & 1] = *(const u16x8*)(zbh + ((s) + 1) * 32);        \
            BL[((u) + 1) & 1] = *(const u16x8*)(zbl + ((s) + 1) * 32);        \
        }                                                                     \
        const u16x8 bh = BH[u], bl = BL[u];                                   \
        u16x8 a;                                                              \
        a = expand8((a0 >> sh) & 0xFF);                                       \
        acc0 = mfma_bf16(a, bh, acc0); acc0 = mfma_bf16(a, bl, acc0);         \
        a = expand8((a1 >> sh) & 0xFF);                                       \
        acc1 = mfma_bf16(a, bh, acc1); acc1 = mfma_bf16(a, bl, acc1);         \
        a = expand8((a2 >> sh) & 0xFF);                                       \
        acc2 = mfma_bf16(a, bh, acc2); acc2 = mfma_bf16(a, bl, acc2);         \
        a = expand8((a3 >> sh) & 0xFF);                                       \
        acc3 = mfma_bf16(a, bh, acc3); acc3 = mfma_bf16(a, bl, acc3);         \
    }

    int sb = 0;
    for (; sb < S - 2; sb += 2) {
        E2V_STEP(sb + 0, 0, true, true)
        E2V_STEP(sb + 1, 1, true, true)
    }
    E2V_STEP(sb + 0, 0, false, true)
    E2V_STEP(sb + 1, 1, false, false)
#undef E2V_STEP

    float* pb = P3 + (((size_t)sp * N_B + n) * 64 + w * 16 + lr) * NV + v0 + lq * 4;
    *(f32x4*)(pb + 0)  = acc0;
    *(f32x4*)(pb + 16) = acc1;
    *(f32x4*)(pb + 32) = acc2;
    *(f32x4*)(pb + 48) = acc3;
}

// ---------------------------------------------------------------------------
// Kernel 5: out[n][v][c] = (sum_sp P3[sp][n][c][v]) / dv + bias  (transpose)
// ---------------------------------------------------------------------------
__global__ __launch_bounds__(512) void k_red3(const float* __restrict__ P3,
                                              const float* __restrict__ dv,
                                              const float* __restrict__ bias,
                                              float* __restrict__ out, int nsp) {
    __shared__ float lt[64][68];
    const int n  = blockIdx.y;
    const int v0 = blockIdx.x * 64;
    const int t  = threadIdx.x;

    {
        const int c   = t >> 3;
        const int vch = (t & 7) * 8;
        float4 s0 = make_float4(0.f, 0.f, 0.f, 0.f), s1 = s0;
        for (int sp = 0; sp < nsp; ++sp) {
            const size_t base = (((size_t)sp * N_B + n) * 64 + c) * NV + v0 + vch;
            const float4 p0 = *(const float4*)&P3[base];
            const float4 p1 = *(const float4*)&P3[base + 4];
            s0.x += p0.x; s0.y += p0.y; s0.z += p0.z; s0.w += p0.w;
            s1.x += p1.x; s1.y += p1.y; s1.z += p1.z; s1.w += p1.w;
        }
        *(float4*)&lt[c][vch]     = s0;
        *(float4*)&lt[c][vch + 4] = s1;
    }
    const int vw  = t >> 3;
    const int cch = (t & 7) * 8;
    const float dsum = dv[(size_t)n * NV + v0 + vw];
    __syncthreads();

    const float rdv = 1.0f / dsum;
    const float4 b0 = *(const float4*)&bias[cch];
    const float4 b1 = *(const float4*)&bias[cch + 4];
    float4 o0, o1;
    o0.x = lt[cch + 0][vw] * rdv + b0.x;
    o0.y = lt[cch + 1][vw] * rdv + b0.y;
    o0.z = lt[cch + 2][vw] * rdv + b0.z;
    o0.w = lt[cch + 3][vw] * rdv + b0.w;
    o1.x = lt[cch + 4][vw] * rdv + b1.x;
    o1.y = lt[cch + 5][vw] * rdv + b1.y;
    o1.z = lt[cch + 6][vw] * rdv + b1.z;
    o1.w = lt[cch + 7][vw] * rdv + b1.w;
    float* dst = out + ((size_t)n * NV + v0 + vw) * 64 + cch;
    *(float4*)dst       = o0;
    *(float4*)(dst + 4) = o1;
}

// ---------------------------------------------------------------------------
extern "C" void kernel_launch(void* const* d_in, const int* in_sizes, int n_in,
                              void* d_out, int out_size, void* d_ws, size_t ws_size,
                              hipStream_t stream) {
    const float* x     = (const float*)d_in[0];
    const float* H     = (const float*)d_in[1];
    const float* theta = (const float*)d_in[2];
    const float* bias  = (const float*)d_in[3];
    float* out = (float*)d_out;

    const size_t yE  = (size_t)N_B * 64 * NV;        // 1,048,576
    const size_t zE  = (size_t)N_B * 64 * NE;        //   524,288
    const size_t HBW = (size_t)N_B * (NV / 16) * (NE / 32) * 16;
    const size_t HTW = (size_t)N_B * (NE / 16) * (NV / 32) * 16;
    const size_t deE = (size_t)N_B * NE;
    const size_t dvE = (size_t)N_B * NV;

    u16* Yh = (u16*)d_ws;
    u16* Yl = Yh + yE;
    u16* Zh = Yl + yE;
    u16* Zl = Zh + zE;
    uint32_t* HB = (uint32_t*)(Zl + zE);
    uint32_t* HT = HB + HBW;
    float* de = (float*)(HT + HTW);
    float* dv = de + deE;
    float* fbase = dv + dvE;

    const size_t fixed_bytes = (size_t)((char*)fbase - (char*)d_ws);
    const size_t avail_f = (ws_size > fixed_bytes) ? (ws_size - fixed_bytes) / 4 : 0;

    // s2/s3 tiers: S must stay even and >= 4
    int s2 = 2, s3 = 1;
    if      (avail_f >= 16 * zE + 8 * yE) { s2 = 16; s3 = 8; }
    else if (avail_f >=  8 * zE + 4 * yE) { s2 = 8;  s3 = 4; }
    else if (avail_f >=  4 * zE + 2 * yE) { s2 = 4;  s3 = 2; }

    float* P2 = fbase;
    float* P3 = P2 + (size_t)s2 * zE;

    k_prep<<<dim3(2048 + 256), 256, 0, stream>>>(H, x, theta, HB, HT, Yh, Yl);
    k_v2e<<<dim3(NE / 64, s2, N_B), 256, 0, stream>>>(HT, HB, Yh, Yl, P2, de, dv);
    k_red2<<<dim3((int)(zE / 4 / 256)), 256, 0, stream>>>(P2, de, Zh, Zl, s2);
    k_e2v<<<dim3(NV / 64, s3, N_B), 256, 0, stream>>>(HB, Zh, Zl, P3);
    k_red3<<<dim3(NV / 64, N_B), 512, 0, stream>>>(P3, dv, bias, out, s3);
}

// Round 18
// 97.213 us; speedup vs baseline: 1.1551x; 1.1040x over previous
//
#include <hip/hip_runtime.h>
#include <hip/hip_bf16.h>
#include <stdint.h>

#define N_B 4
#define NV 4096
#define NE 2048

typedef float    f32x4  __attribute__((ext_vector_type(4)));
typedef __bf16   bf16x8 __attribute__((ext_vector_type(8)));
typedef unsigned short u16;
typedef u16      u16x8  __attribute__((ext_vector_type(8)));
typedef uint32_t u32x4  __attribute__((ext_vector_type(4)));

__device__ __forceinline__ u16 f2bf_rne(float f) {
    uint32_t u = __builtin_bit_cast(uint32_t, f);
    u += 0x7FFFu + ((u >> 16) & 1u);
    return (u16)(u >> 16);
}
__device__ __forceinline__ float bf2f(u16 h) {
    uint32_t u = ((uint32_t)h) << 16;
    return __builtin_bit_cast(float, u);
}
__device__ __forceinline__ f32x4 mfma_bf16(u16x8 a, u16x8 b, f32x4 c) {
    return __builtin_amdgcn_mfma_f32_16x16x32_bf16(
        __builtin_bit_cast(bf16x8, a), __builtin_bit_cast(bf16x8, b), c, 0, 0, 0);
}
// 8 bits -> 8 bf16 (1.0/0.0). u16 lane j = bit j.
__device__ __forceinline__ u16x8 expand8(uint32_t byte) {
    u32x4 w;
#pragma unroll
    for (int p = 0; p < 4; ++p) {
        const uint32_t lo = (byte >> (2 * p)) & 1u;
        const uint32_t hi = (byte >> (2 * p + 1)) & 1u;
        w[p] = (lo | (hi << 16)) * 0x3F80u;
    }
    return __builtin_bit_cast(u16x8, w);
}

// ---------------------------------------------------------------------------
// Kernel P: ballot-free pack (R13-proven structure). One 64x64 tile per
// block; LDS 17.4 KB (rows padded to 68 floats = 16B-aligned, so the
// HB-half build uses ds_read_b128). Each thread builds ONE 32-bit word.
//   HB[n][v>>4][e/32][v&15]  (bit = e&31)
//   HT[n][e>>4][v/32][e&15]  (bit = v&31)
// ---------------------------------------------------------------------------
__global__ __launch_bounds__(256) void k_pack(const float* __restrict__ H,
                                              uint32_t* __restrict__ HB,
                                              uint32_t* __restrict__ HT) {
    __shared__ float tile[64][68];   // 68 = 4*17: rows 16B-aligned, banks coprime
    const int bid = blockIdx.x;
    const int ex = bid & 31, vy = (bid >> 5) & 63, n = bid >> 11;
    const int e0 = ex * 64, v0 = vy * 64;
    const int t = threadIdx.x;
    const float* __restrict__ Hn = H + ((size_t)n * NV + v0) * NE + e0;

#pragma unroll
    for (int i = 0; i < 4; ++i) {
        const int idx = i * 256 + t;
        const int row = idx >> 4;
        const int q = (idx & 15) * 4;
        const float4 hv = *(const float4*)(Hn + (size_t)row * NE + q);
        *(float4*)&tile[row][q] = hv;   // (68*row + q) % 4 == 0 -> aligned
    }
    __syncthreads();

    if (t < 128) {
        // HB word: row v (64), e-halfword we (2). b128 reads, rows aligned.
        const int v = t >> 1, we = t & 1;
        uint32_t u = 0;
#pragma unroll
        for (int q = 0; q < 8; ++q) {
            const f32x4 f = *(const f32x4*)&tile[v][we * 32 + q * 4];
            u |= (f[0] != 0.0f ? 1u : 0u) << (4 * q + 0);
            u |= (f[1] != 0.0f ? 1u : 0u) << (4 * q + 1);
            u |= (f[2] != 0.0f ? 1u : 0u) << (4 * q + 2);
            u |= (f[3] != 0.0f ? 1u : 0u) << (4 * q + 3);
        }
        HB[(((size_t)n * (NV / 16) + ((v0 + v) >> 4)) * (NE / 32) + (e0 >> 5) + we) * 16 +
           ((v0 + v) & 15)] = u;
    } else {
        // HT word: col e (64), v-halfword wv (2). bank (4j+e)%32: 2-way, free.
        const int e = (t - 128) >> 1, wv = t & 1;
        uint32_t u = 0;
#pragma unroll
        for (int j = 0; j < 32; ++j)
            u |= (tile[wv * 32 + j][e] != 0.0f) ? (1u << j) : 0u;
        HT[(((size_t)n * (NE / 16) + ((e0 + e) >> 4)) * (NV / 32) + (v0 >> 5) + wv) * 16 +
           ((e0 + e) & 15)] = u;
    }
}

// ---------------------------------------------------------------------------
// Kernel 1: Yht_{h,l}[n][c][v] (bf16 hi/lo) = transpose of x@theta.
// ---------------------------------------------------------------------------
__global__ __launch_bounds__(256) void k_xtheta(const float* __restrict__ x,
                                                const float* __restrict__ th,
                                                u16* __restrict__ Yh,
                                                u16* __restrict__ Yl) {
    __shared__ float xs[64][65];   // [v][k]
    __shared__ float ts[64][65];   // [k][c]
    const int t = threadIdx.x;
    const int n  = blockIdx.x >> 6;
    const int v0 = (blockIdx.x & 63) * 64;

#pragma unroll
    for (int i = 0; i < 4; ++i) {
        const int idx = i * 256 + t;
        const int row = idx >> 4, q = (idx & 15) * 4;
        const float4 xv = *(const float4*)&x[((size_t)(n * NV + v0 + row)) * 64 + q];
        const float4 tv = *(const float4*)&th[(size_t)row * 64 + q];
        xs[row][q] = xv.x; xs[row][q + 1] = xv.y; xs[row][q + 2] = xv.z; xs[row][q + 3] = xv.w;
        ts[row][q] = tv.x; ts[row][q + 1] = tv.y; ts[row][q + 2] = tv.z; ts[row][q + 3] = tv.w;
    }
    __syncthreads();

    const int v4 = (t & 15) * 4;
    const int c4 = (t >> 4) * 4;
    float acc[4][4] = {};   // [c][v]
#pragma unroll
    for (int k = 0; k < 64; ++k) {
        float tv[4], xv[4];
#pragma unroll
        for (int i = 0; i < 4; ++i) { tv[i] = ts[k][c4 + i]; xv[i] = xs[v4 + i][k]; }
#pragma unroll
        for (int i = 0; i < 4; ++i)
#pragma unroll
            for (int j = 0; j < 4; ++j) acc[i][j] += tv[i] * xv[j];
    }
#pragma unroll
    for (int i = 0; i < 4; ++i) {
        ushort4 hi, lo;
        u16 h;
        h = f2bf_rne(acc[i][0]); hi.x = h; lo.x = f2bf_rne(acc[i][0] - bf2f(h));
        h = f2bf_rne(acc[i][1]); hi.y = h; lo.y = f2bf_rne(acc[i][1] - bf2f(h));
        h = f2bf_rne(acc[i][2]); hi.z = h; lo.z = f2bf_rne(acc[i][2] - bf2f(h));
        h = f2bf_rne(acc[i][3]); hi.w = h; lo.w = f2bf_rne(acc[i][3] - bf2f(h));
        const size_t o = ((size_t)n * 64 + c4 + i) * NV + v0 + v4;
        *(ushort4*)&Yh[o] = hi;
        *(ushort4*)&Yl[o] = lo;
    }
}

// ---------------------------------------------------------------------------
// Kernel 2: vertex->edge MFMA partials + folded degree-from-popcount.
//   P2[sp][n][c][e] = sum_{v in Krange} H[n,v,e]*(Yh+Yl)[n,v,c]
// XCD swizzle; launch_bounds(256,8); A depth-2 + B depth-1.
// ---------------------------------------------------------------------------
__global__ __launch_bounds__(256, 8) void k_v2e(const uint32_t* __restrict__ HT,
                                                const uint32_t* __restrict__ HB,
                                                const u16* __restrict__ Yh,
                                                const u16* __restrict__ Yl,
                                                float* __restrict__ P2,
                                                float* __restrict__ de,
                                                float* __restrict__ dv) {
    const int t = threadIdx.x;
    const int s2 = gridDim.y;
    const int lin = blockIdx.x + 32 * (blockIdx.y + s2 * blockIdx.z);
    const int nb = 32 * s2 * N_B;

    // ---- folded degree collapse via popcount (grid-stride, t<64) ----
    if (t < 64) {
        const int total = N_B * NE + N_B * NV;
        for (int id = lin * 64 + t; id < total; id += nb * 64) {
            if (id < N_B * NE) {
                const int n_ = id >> 11, e = id & (NE - 1);
                const uint32_t* p =
                    HT + ((size_t)n_ * (NE / 16) + (e >> 4)) * ((NV / 32) * 16) + (e & 15);
                uint32_t s = 0;
#pragma unroll 4
                for (int wv = 0; wv < NV / 32; ++wv) s += __popc(p[(size_t)wv * 16]);
                de[id] = (float)s;
            } else {
                const int j = id - N_B * NE;
                const int n_ = j >> 12, v = j & (NV - 1);
                const uint32_t* p =
                    HB + ((size_t)n_ * (NV / 16) + (v >> 4)) * ((NE / 32) * 16) + (v & 15);
                uint32_t s = 0;
#pragma unroll 4
                for (int we = 0; we < NE / 32; ++we) s += __popc(p[(size_t)we * 16]);
                dv[j] = (float)s;
            }
        }
    }

    // ---- XCD-swizzled work decode ----
    const int wid = (lin & 7) * (nb >> 3) + (lin >> 3);
    const int n   = wid / (32 * s2);
    const int rem = wid % (32 * s2);
    const int sp  = rem >> 5;
    const int e0  = (rem & 31) * 64;

    const int krange = NV / s2;
    const int kk0 = sp * krange;
    const int S   = krange / 32;   // 8 at s2=16

    const int w = t >> 6, l = t & 63;
    const int lq = l >> 4, lr = l & 15;
    const int sh = lq * 8;
    const int hstride = (NV / 32) * 16;

    const uint32_t* __restrict__ ht =
        HT + ((size_t)n * (NE / 16) + (e0 >> 4)) * hstride + (kk0 >> 5) * 16 + lr;
    const u16* __restrict__ ybh = Yh + ((size_t)n * 64 + w * 16 + lr) * NV + kk0 + lq * 8;
    const u16* __restrict__ ybl = Yl + ((size_t)n * 64 + w * 16 + lr) * NV + kk0 + lq * 8;

    f32x4 acc0 = {0.f,0.f,0.f,0.f}, acc1 = acc0, acc2 = acc0, acc3 = acc0;

    uint32_t A[2][4];
#pragma unroll
    for (int d = 0; d < 2; ++d) {
        A[d][0] = ht[0 * hstride + d * 16];
        A[d][1] = ht[1 * hstride + d * 16];
        A[d][2] = ht[2 * hstride + d * 16];
        A[d][3] = ht[3 * hstride + d * 16];
    }
    u16x8 BH[2], BL[2];
    BH[0] = *(const u16x8*)ybh;
    BL[0] = *(const u16x8*)ybl;

#define V2E_STEP(s, u, GA, GB)                                                \
    {                                                                         \
        const uint32_t a0 = A[u][0], a1 = A[u][1], a2 = A[u][2], a3 = A[u][3];\
        if (GA) {                                                             \
            A[u][0] = ht[0 * hstride + ((s) + 2) * 16];                       \
            A[u][1] = ht[1 * hstride + ((s) + 2) * 16];                       \
            A[u][2] = ht[2 * hstride + ((s) + 2) * 16];                       \
            A[u][3] = ht[3 * hstride + ((s) + 2) * 16];                       \
        }                                                                     \
        if (GB) {                                                             \
            BH[((u) + 1) & 1] = *(const u16x8*)(ybh + ((s) + 1) * 32);        \
            BL[((u) + 1) & 1] = *(const u16x8*)(ybl + ((s) + 1) * 32);        \
        }                                                                     \
        const u16x8 bh = BH[u], bl = BL[u];                                   \
        u16x8 a;                                                              \
        a = expand8((a0 >> sh) & 0xFF);                                       \
        acc0 = mfma_bf16(a, bh, acc0); acc0 = mfma_bf16(a, bl, acc0);         \
        a = expand8((a1 >> sh) & 0xFF);                                       \
        acc1 = mfma_bf16(a, bh, acc1); acc1 = mfma_bf16(a, bl, acc1);         \
        a = expand8((a2 >> sh) & 0xFF);                                       \
        acc2 = mfma_bf16(a, bh, acc2); acc2 = mfma_bf16(a, bl, acc2);         \
        a = expand8((a3 >> sh) & 0xFF);                                       \
        acc3 = mfma_bf16(a, bh, acc3); acc3 = mfma_bf16(a, bl, acc3);         \
    }

    int sb = 0;
    for (; sb < S - 2; sb += 2) {
        V2E_STEP(sb + 0, 0, true, true)
        V2E_STEP(sb + 1, 1, true, true)
    }
    V2E_STEP(sb + 0, 0, false, true)
    V2E_STEP(sb + 1, 1, false, false)
#undef V2E_STEP

    // D: row e = e0 + eb*16 + lq*4 + reg, col c = w*16 + lr
    float* pb = P2 + (((size_t)sp * N_B + n) * 64 + w * 16 + lr) * NE + e0 + lq * 4;
    *(f32x4*)(pb + 0)  = acc0;
    *(f32x4*)(pb + 16) = acc1;
    *(f32x4*)(pb + 32) = acc2;
    *(f32x4*)(pb + 48) = acc3;
}

// ---------------------------------------------------------------------------
// Kernel 3: Z_{h,l}[n][c][e] = bf16 hi/lo of (sum_sp P2)/de
// ---------------------------------------------------------------------------
__global__ __launch_bounds__(256) void k_red2(const float* __restrict__ P2,
                                              const float* __restrict__ de,
                                              u16* __restrict__ Zh,
                                              u16* __restrict__ Zl, int nsp) {
    const int i = blockIdx.x * 256 + threadIdx.x;   // 0..131071
    const int row = i >> 9;                          // n*64 + c
    const int e4  = (i & 511) * 4;
    const int n   = row >> 6;

    float4 a = make_float4(0.f, 0.f, 0.f, 0.f);
    for (int sp = 0; sp < nsp; ++sp) {
        const float4 p = *(const float4*)&P2[((size_t)sp * 256 + row) * NE + e4];
        a.x += p.x; a.y += p.y; a.z += p.z; a.w += p.w;
    }
    const float4 d = *(const float4*)&de[(size_t)n * NE + e4];
    float z[4] = {a.x / d.x, a.y / d.y, a.z / d.z, a.w / d.w};
    ushort4 hi, lo;
    u16 h;
    h = f2bf_rne(z[0]); hi.x = h; lo.x = f2bf_rne(z[0] - bf2f(h));
    h = f2bf_rne(z[1]); hi.y = h; lo.y = f2bf_rne(z[1] - bf2f(h));
    h = f2bf_rne(z[2]); hi.z = h; lo.z = f2bf_rne(z[2] - bf2f(h));
    h = f2bf_rne(z[3]); hi.w = h; lo.w = f2bf_rne(z[3] - bf2f(h));
    *(ushort4*)&Zh[(size_t)row * NE + e4] = hi;
    *(ushort4*)&Zl[(size_t)row * NE + e4] = lo;
}

// ---------------------------------------------------------------------------
// Kernel 4: edge->vertex MFMA partials. Same structure as k_v2e.
// ---------------------------------------------------------------------------
__global__ __launch_bounds__(256, 8) void k_e2v(const uint32_t* __restrict__ HB,
                                                const u16* __restrict__ Zh,
                                                const u16* __restrict__ Zl,
                                                float* __restrict__ P3) {
    const int t = threadIdx.x;
    const int s3 = gridDim.y;
    const int lin = blockIdx.x + 64 * (blockIdx.y + s3 * blockIdx.z);
    const int nb = 64 * s3 * N_B;

    const int wid = (lin & 7) * (nb >> 3) + (lin >> 3);
    const int n   = wid / (64 * s3);
    const int rem = wid % (64 * s3);
    const int sp  = rem >> 6;
    const int v0  = (rem & 63) * 64;

    const int krange = NE / s3;
    const int kk0 = sp * krange;
    const int S   = krange / 32;   // 8 at s3=8

    const int w = t >> 6, l = t & 63;
    const int lq = l >> 4, lr = l & 15;
    const int sh = lq * 8;
    const int estride = (NE / 32) * 16;

    const uint32_t* __restrict__ hb =
        HB + ((size_t)n * (NV / 16) + (v0 >> 4)) * estride + (kk0 >> 5) * 16 + lr;
    const u16* __restrict__ zbh = Zh + ((size_t)n * 64 + w * 16 + lr) * NE + kk0 + lq * 8;
    const u16* __restrict__ zbl = Zl + ((size_t)n * 64 + w * 16 + lr) * NE + kk0 + lq * 8;

    f32x4 acc0 = {0.f,0.f,0.f,0.f}, acc1 = acc0, acc2 = acc0, acc3 = acc0;

    uint32_t A[2][4];
#pragma unroll
    for (int d = 0; d < 2; ++d) {
        A[d][0] = hb[0 * estride + d * 16];
        A[d][1] = hb[1 * estride + d * 16];
        A[d][2] = hb[2 * estride + d * 16];
        A[d][3] = hb[3 * estride + d * 16];
    }
    u16x8 BH[2], BL[2];
    BH[0] = *(const u16x8*)zbh;
    BL[0] = *(const u16x8*)zbl;

#define E2V_STEP(s, u, GA, GB)                                                \
    {                                                                         \
        const uint32_t a0 = A[u][0], a1 = A[u][1], a2 = A[u][2], a3 = A[u][3];\
        if (GA) {                                                             \
            A[u][0] = hb[0 * estride + ((s) + 2) * 16];                       \
            A[u][1] = hb[1 * estride + ((s) + 2) * 16];                       \
            A[u][2] = hb[2 * estride + ((s) + 2) * 16];                       \
            A[u][3] = hb[3 * estride + ((s) + 2) * 16];                       \
        }                                                                     \
        if (GB) {                                                             \
            BH[((u) + 1) & 1] = *(const u16x8*)(zbh + ((s) + 1) * 32);        \
            BL[((u) + 1) & 1] = *(const u16x8*)(zbl + ((s) + 1) * 32);        \
        }                                                                     \
        const u16x8 bh = BH[u], bl = BL[u];                                   \
        u16x8 a;                                                              \
        a = expand8((a0 >> sh) & 0xFF);                                       \
        acc0 = mfma_bf16(a, bh, acc0); acc0 = mfma_bf16(a, bl, acc0);         \
        a = expand8((a1 >> sh) & 0xFF);                                       \
        acc1 = mfma_bf16(a, bh, acc1); acc1 = mfma_bf16(a, bl, acc1);         \
        a = expand8((a2 >> sh) & 0xFF);                                       \
        acc2 = mfma_bf16(a, bh, acc2); acc2 = mfma_bf16(a, bl, acc2);         \
        a = expand8((a3 >> sh) & 0xFF);                                       \
        acc3 = mfma_bf16(a, bh, acc3); acc3 = mfma_bf16(a, bl, acc3);         \
    }

    int sb = 0;
    for (; sb < S - 2; sb += 2) {
        E2V_STEP(sb + 0, 0, true, true)
        E2V_STEP(sb + 1, 1, true, true)
    }
    E2V_STEP(sb + 0, 0, false, true)
    E2V_STEP(sb + 1, 1, false, false)
#undef E2V_STEP

    float* pb = P3 + (((size_t)sp * N_B + n) * 64 + w * 16 + lr) * NV + v0 + lq * 4;
    *(f32x4*)(pb + 0)  = acc0;
    *(f32x4*)(pb + 16) = acc1;
    *(f32x4*)(pb + 32) = acc2;
    *(f32x4*)(pb + 48) = acc3;
}

// ---------------------------------------------------------------------------
// Kernel 5: out[n][v][c] = (sum_sp P3[sp][n][c][v]) / dv + bias  (transpose)
// ---------------------------------------------------------------------------
__global__ __launch_bounds__(512) void k_red3(const float* __restrict__ P3,
                                              const float* __restrict__ dv,
                                              const float* __restrict__ bias,
                                              float* __restrict__ out, int nsp) {
    __shared__ float lt[64][68];
    const int n  = blockIdx.y;
    const int v0 = blockIdx.x * 64;
    const int t  = threadIdx.x;

    {
        const int c   = t >> 3;
        const int vch = (t & 7) * 8;
        float4 s0 = make_float4(0.f, 0.f, 0.f, 0.f), s1 = s0;
        for (int sp = 0; sp < nsp; ++sp) {
            const size_t base = (((size_t)sp * N_B + n) * 64 + c) * NV + v0 + vch;
            const float4 p0 = *(const float4*)&P3[base];
            const float4 p1 = *(const float4*)&P3[base + 4];
            s0.x += p0.x; s0.y += p0.y; s0.z += p0.z; s0.w += p0.w;
            s1.x += p1.x; s1.y += p1.y; s1.z += p1.z; s1.w += p1.w;
        }
        *(float4*)&lt[c][vch]     = s0;
        *(float4*)&lt[c][vch + 4] = s1;
    }
    const int vw  = t >> 3;
    const int cch = (t & 7) * 8;
    const float dsum = dv[(size_t)n * NV + v0 + vw];
    __syncthreads();

    const float rdv = 1.0f / dsum;
    const float4 b0 = *(const float4*)&bias[cch];
    const float4 b1 = *(const float4*)&bias[cch + 4];
    float4 o0, o1;
    o0.x = lt[cch + 0][vw] * rdv + b0.x;
    o0.y = lt[cch + 1][vw] * rdv + b0.y;
    o0.z = lt[cch + 2][vw] * rdv + b0.z;
    o0.w = lt[cch + 3][vw] * rdv + b0.w;
    o1.x = lt[cch + 4][vw] * rdv + b1.x;
    o1.y = lt[cch + 5][vw] * rdv + b1.y;
    o1.z = lt[cch + 6][vw] * rdv + b1.z;
    o1.w = lt[cch + 7][vw] * rdv + b1.w;
    float* dst = out + ((size_t)n * NV + v0 + vw) * 64 + cch;
    *(float4*)dst       = o0;
    *(float4*)(dst + 4) = o1;
}

// ---------------------------------------------------------------------------
extern "C" void kernel_launch(void* const* d_in, const int* in_sizes, int n_in,
                              void* d_out, int out_size, void* d_ws, size_t ws_size,
                              hipStream_t stream) {
    const float* x     = (const float*)d_in[0];
    const float* H     = (const float*)d_in[1];
    const float* theta = (const float*)d_in[2];
    const float* bias  = (const float*)d_in[3];
    float* out = (float*)d_out;

    const size_t yE  = (size_t)N_B * 64 * NV;        // 1,048,576
    const size_t zE  = (size_t)N_B * 64 * NE;        //   524,288
    const size_t HBW = (size_t)N_B * (NV / 16) * (NE / 32) * 16;
    const size_t HTW = (size_t)N_B * (NE / 16) * (NV / 32) * 16;
    const size_t deE = (size_t)N_B * NE;
    const size_t dvE = (size_t)N_B * NV;

    u16* Yh = (u16*)d_ws;
    u16* Yl = Yh + yE;
    u16* Zh = Yl + yE;
    u16* Zl = Zh + zE;
    uint32_t* HB = (uint32_t*)(Zl + zE);
    uint32_t* HT = HB + HBW;
    float* de = (float*)(HT + HTW);
    float* dv = de + deE;
    float* fbase = dv + dvE;

    const size_t fixed_bytes = (size_t)((char*)fbase - (char*)d_ws);
    const size_t avail_f = (ws_size > fixed_bytes) ? (ws_size - fixed_bytes) / 4 : 0;

    // s2/s3 tiers: S must stay even and >= 4
    int s2 = 2, s3 = 1;
    if      (avail_f >= 16 * zE + 8 * yE) { s2 = 16; s3 = 8; }
    else if (avail_f >=  8 * zE + 4 * yE) { s2 = 8;  s3 = 4; }
    else if (avail_f >=  4 * zE + 2 * yE) { s2 = 4;  s3 = 2; }

    float* P2 = fbase;
    float* P3 = P2 + (size_t)s2 * zE;

    k_pack<<<dim3(8192), 256, 0, stream>>>(H, HB, HT);
    k_xtheta<<<dim3(N_B * NV / 64), 256, 0, stream>>>(x, theta, Yh, Yl);
    k_v2e<<<dim3(NE / 64, s2, N_B), 256, 0, stream>>>(HT, HB, Yh, Yl, P2, de, dv);
    k_red2<<<dim3((int)(zE / 4 / 256)), 256, 0, stream>>>(P2, de, Zh, Zl, s2);
    k_e2v<<<dim3(NV / 64, s3, N_B), 256, 0, stream>>>(HB, Zh, Zl, P3);
    k_red3<<<dim3(NV / 64, N_B), 512, 0, stream>>>(P3, dv, bias, out, s3);
}